// Round 2
// baseline (465.745 us; speedup 1.0000x reference)
//
#include <hip/hip_runtime.h>

#define NT 32768
#define DI 36
#define HH 64
#define G3 192
#define LH 20

__device__ __forceinline__ float readlane_f(float v, int l) {
    union { float f; int i; } u;
    u.f = v;
    u.i = __builtin_amdgcn_readlane(u.i, l);
    return u.f;
}

__device__ __forceinline__ float sigmoid_f(float x) {
    return 1.f / (1.f + __expf(-x));
}
// tanh(x) = 1 - 2/(1+e^{2x}); overflow-safe
__device__ __forceinline__ float tanh_f(float x) {
    return 1.f - 2.f / (1.f + __expf(2.f * x));
}

// gi layout per t (192 floats): [2j]=r-gate j, [2j+1]=z-gate j, [128+j]=n-gate j.
// Thread tid owns output column `tid`; the W_ih row it needs is rrow(tid):
//   tid<128: gate=tid&1, j=tid>>1 -> row (tid&1)*64 + (tid>>1);  tid>=128: row tid.
__global__ __launch_bounds__(192) void prep_kernel(
    const float* __restrict__ emb, const float* __restrict__ W_ih,
    const float* __restrict__ b_ih, const float* __restrict__ b_hh,
    const float* __restrict__ W1,
    float* __restrict__ gi, float* __restrict__ W1T)
{
    __shared__ float Wt[DI][G3 + 1];   // Wt[k][row]
    __shared__ float Et[DI][36];       // Et[k][i], 32 t's + pad (rows 16B-aligned)
    const int tid = threadIdx.x;
    const int t0 = blockIdx.x * 32;
    const int rrow = (tid < 128) ? ((tid & 1) * 64 + (tid >> 1)) : tid;

    for (int i = tid; i < G3 * DI; i += 192)        // coalesced read, by row
        Wt[i % DI][i / DI] = W_ih[i];
    for (int i = tid; i < 32 * DI; i += 192)        // emb chunk, coalesced
        Et[i % DI][i / DI] = emb[(size_t)t0 * DI + i];
    if (blockIdx.x == 0) {
        for (int i = tid; i < HH * HH; i += 192)
            W1T[(i & 63) * HH + (i >> 6)] = W1[i];
    }
    __syncthreads();

    float acc[32];
#pragma unroll
    for (int i = 0; i < 32; ++i) acc[i] = 0.f;
    for (int k = 0; k < DI; ++k) {
        const float w = Wt[k][rrow];                 // 2-way bank alias: free
#pragma unroll
        for (int i4 = 0; i4 < 8; ++i4) {
            const float4 e = *(const float4*)&Et[k][i4 * 4];  // broadcast b128
            acc[i4 * 4 + 0] = fmaf(e.x, w, acc[i4 * 4 + 0]);
            acc[i4 * 4 + 1] = fmaf(e.y, w, acc[i4 * 4 + 1]);
            acc[i4 * 4 + 2] = fmaf(e.z, w, acc[i4 * 4 + 2]);
            acc[i4 * 4 + 3] = fmaf(e.w, w, acc[i4 * 4 + 3]);
        }
    }
    const float bias = b_ih[rrow] + (rrow < 128 ? b_hh[rrow] : 0.f);
#pragma unroll
    for (int i = 0; i < 32; ++i)
        gi[(size_t)(t0 + i) * G3 + tid] = acc[i] + bias;   // coalesced
}

// Main kernel: block = 512 threads (8 waves), 128 t/block, grid 256 (1 block/CU).
// Wave tt owns t in [T0+16*tt, T0+16*tt+16); lane j holds h[t][j].
// LDS: S_rz[k][2j]=(Wr[k][j],Wz[k][j]) stride 130; S_n[k][j] stride 65.
__global__ __launch_bounds__(512, 2) void gru_kernel(
    const float* __restrict__ gi, const float* __restrict__ W_hh,
    const float* __restrict__ b_hh, const float* __restrict__ b1,
    const float* __restrict__ W2, const float* __restrict__ b2,
    const float* __restrict__ W1T, const int* __restrict__ dones,
    float* __restrict__ out)
{
    __shared__ float S[HH * 130 + HH * 65];   // 12480 floats = 49.9 KB
    __shared__ int sfirst[128];
    float* const S_rz = S;
    float* const S_n  = S + HH * 130;
    const int tid = threadIdx.x;
    const int lane = tid & 63;
    const int tt = tid >> 6;
    const int T0 = blockIdx.x * 128;
    const int tl0 = tt * 16;

    // Stage W_hh: consecutive tid -> consecutive k (coalesced global reads)
    for (int i = tid; i < HH * HH; i += 512) {
        const int j = i >> 6, k = i & 63;
        S_rz[k * 130 + 2 * j]     = W_hh[j * HH + k];            // r
        S_rz[k * 130 + 2 * j + 1] = W_hh[(64 + j) * HH + k];     // z
        S_n [k * 65 + j]          = W_hh[(128 + j) * HH + k];    // n
    }
    // win_start is purely local: window <= 20 -> only dones[t-19..t-1] matter.
    if (tid < 128) {
        const int t = T0 + tid;
        int lo = t - (LH - 1); if (lo < 0) lo = 0;
        int ws = lo;
        for (int j = t - 1; j >= lo; --j)
            if (dones[j] != 0) { ws = j + 1; break; }
        sfirst[tid] = ws - (t - (LH - 1));   // first valid window step s
    }
    __syncthreads();

    const float bn = b_hh[128 + lane];
    int sfr[16];
    float h[16];
#pragma unroll
    for (int i = 0; i < 16; ++i) {
        h[i] = 0.f;
        sfr[i] = __builtin_amdgcn_readfirstlane(sfirst[tl0 + i]);  // SGPR
    }

    for (int s = 0; s < LH; ++s) {
        // Prefetch gi for this step: b64 (r,z) + b32 (n), coalesced, issued
        // before the k-loop so ~6k cycles of FMA hide the VMEM latency.
        float2 grz[16]; float gn[16];
#pragma unroll
        for (int i = 0; i < 16; ++i) {
            int g = T0 + tl0 + i - (LH - 1) + s;
            g = g < 0 ? 0 : g;                       // masked anyway when invalid
            const float* p = gi + (size_t)g * G3;
            grz[i] = *(const float2*)(p + 2 * lane);
            gn[i]  = p[128 + lane];
        }
        float2 arz[16]; float an[16];
#pragma unroll
        for (int i = 0; i < 16; ++i) { arz[i] = make_float2(0.f, 0.f); an[i] = 0.f; }
#pragma unroll 4
        for (int k = 0; k < HH; ++k) {
            const float2 wrz = *(const float2*)(S_rz + k * 130 + 2 * lane); // ds_read_b64
            const float  wn  = S_n[k * 65 + lane];                          // conflict-free
#pragma unroll
            for (int i = 0; i < 16; ++i) {
                const float hv = readlane_f(h[i], k);     // h[t][k], SGPR broadcast
                arz[i].x = fmaf(hv, wrz.x, arz[i].x);
                arz[i].y = fmaf(hv, wrz.y, arz[i].y);
                an[i]    = fmaf(hv, wn,    an[i]);
            }
        }
#pragma unroll
        for (int i = 0; i < 16; ++i) {
            const float r  = sigmoid_f(arz[i].x + grz[i].x);
            const float z  = sigmoid_f(arz[i].y + grz[i].y);
            const float nc = tanh_f(gn[i] + r * (an[i] + bn));
            const float hn = fmaf(z, h[i] - nc, nc);      // (1-z)*nc + z*h
            h[i] = (s >= sfr[i]) ? hn : h[i];             // scalar cmp + cndmask
        }
    }

    // MLP layer 1: hid[t][m] = relu(b1[m] + sum_k W1[m][k] h[t][k]), m = lane
    float a1[16];
#pragma unroll
    for (int i = 0; i < 16; ++i) a1[i] = 0.f;
    for (int k = 0; k < HH; ++k) {
        const float w = W1T[k * HH + lane];   // L1-resident 16 KB, coalesced
#pragma unroll
        for (int i = 0; i < 16; ++i)
            a1[i] = fmaf(readlane_f(h[i], k), w, a1[i]);
    }
    const float bb1 = b1[lane];
    __syncthreads();                      // all waves done with W in LDS
#pragma unroll
    for (int i = 0; i < 16; ++i)          // reuse S as hid_T[m][t], stride 132
        S[lane * 132 + tl0 + i] = fmaxf(a1[i] + bb1, 0.f);
    __syncthreads();

    // MLP layer 2: one output element per thread
    {
        const int to = tid >> 2, c = tid & 3;
        const float* w2 = W2 + c * HH;
        float a = 0.f;
        for (int m = 0; m < HH; ++m)
            a = fmaf(S[m * 132 + to], w2[m], a);    // 16 banks + broadcast: clean
        out[(size_t)(T0 + to) * 4 + c] = a + b2[c]; // coalesced
    }
}

extern "C" void kernel_launch(void* const* d_in, const int* in_sizes, int n_in,
                              void* d_out, int out_size, void* d_ws, size_t ws_size,
                              hipStream_t stream) {
    const float* emb  = (const float*)d_in[0];
    const float* W_ih = (const float*)d_in[1];
    const float* W_hh = (const float*)d_in[2];
    const float* b_ih = (const float*)d_in[3];
    const float* b_hh = (const float*)d_in[4];
    const float* W1   = (const float*)d_in[5];
    const float* b1   = (const float*)d_in[6];
    const float* W2   = (const float*)d_in[7];
    const float* b2   = (const float*)d_in[8];
    const int*   dn   = (const int*)d_in[9];

    float* gi  = (float*)d_ws;                         // 32768*192*4 = 25.2 MB
    float* W1T = (float*)d_ws + (size_t)NT * G3;       // +16 KB
    float* o   = (float*)d_out;

    prep_kernel<<<NT / 32, 192, 0, stream>>>(emb, W_ih, b_ih, b_hh, W1, gi, W1T);
    gru_kernel<<<NT / 128, 512, 0, stream>>>(gi, W_hh, b_hh, b1, W2, b2, W1T, dn, o);
}

// Round 3
// 188.627 us; speedup vs baseline: 2.4691x; 2.4691x over previous
//
#include <hip/hip_runtime.h>

#define NT 32768
#define DI 36
#define HH 64
#define G3 192
#define LH 20

typedef __attribute__((ext_vector_type(8))) short bf16x8;
typedef __attribute__((ext_vector_type(4))) float f32x4;
typedef __attribute__((ext_vector_type(4))) int int4v;

union frag_cast { int4v i4; bf16x8 h8; };

__device__ __forceinline__ unsigned short f2bf(float f) {  // RNE fp32->bf16
    union { float f; unsigned u; } x; x.f = f;
    unsigned r = x.u + 0x7FFFu + ((x.u >> 16) & 1u);
    return (unsigned short)(r >> 16);
}
__device__ __forceinline__ float bf2f(unsigned short h) {
    union { float f; unsigned u; } x; x.u = ((unsigned)h) << 16;
    return x.f;
}
__device__ __forceinline__ float fast_sigmoid(float x) {
    // 1/(1+2^(-x*log2e)) ; rcp/exp2 approx ok vs 2.9e-2 threshold
    return __builtin_amdgcn_rcpf(1.f + __builtin_amdgcn_exp2f(-1.44269504089f * x));
}
__device__ __forceinline__ float fast_tanh(float x) {
    // 1 - 2/(1+2^(2x*log2e)); saturates correctly at +-inf
    return 1.f - 2.f * __builtin_amdgcn_rcpf(1.f + __builtin_amdgcn_exp2f(2.88539008178f * x));
}

// Kernel 1: gi_T[j][t] = emb[t,:].W_ih[j,:] + b_ih[j] + (j<128 ? b_hh[j] : 0)
// (transposed so gru loads along t are coalesced). Block 0 also emits the
// W_hh MFMA A-fragments (bf16 hi/lo) in exact per-lane order.
__global__ __launch_bounds__(192, 2) void prep_kernel(
    const float* __restrict__ emb, const float* __restrict__ W_ih,
    const float* __restrict__ b_ih, const float* __restrict__ b_hh,
    const float* __restrict__ W_hh,
    float* __restrict__ giT, int4v* __restrict__ wfrag)
{
    __shared__ float Wt[DI][G3 + 1];   // Wt[k][j]
    __shared__ float Et[DI][36];       // Et[k][t_local], rows 144B (16B-aligned)
    const int tid = threadIdx.x;
    const int t0 = blockIdx.x * 32;

    for (int i = tid; i < G3 * DI; i += 192)
        Wt[i % DI][i / DI] = W_ih[i];
    for (int i = tid; i < 32 * DI; i += 192)
        Et[i % DI][i / DI] = emb[(size_t)t0 * DI + i];
    __syncthreads();

    float acc[32];
#pragma unroll
    for (int i = 0; i < 32; ++i) acc[i] = 0.f;
    for (int k = 0; k < DI; ++k) {
        const float w = Wt[k][tid];                       // 2-way alias: free
#pragma unroll
        for (int i4 = 0; i4 < 8; ++i4) {
            const float4 e = *(const float4*)&Et[k][i4 * 4];  // broadcast b128
            acc[i4 * 4 + 0] = fmaf(e.x, w, acc[i4 * 4 + 0]);
            acc[i4 * 4 + 1] = fmaf(e.y, w, acc[i4 * 4 + 1]);
            acc[i4 * 4 + 2] = fmaf(e.z, w, acc[i4 * 4 + 2]);
            acc[i4 * 4 + 3] = fmaf(e.w, w, acc[i4 * 4 + 3]);
        }
    }
    const float bias = b_ih[tid] + (tid < 128 ? b_hh[tid] : 0.f);
#pragma unroll
    for (int i4 = 0; i4 < 8; ++i4) {
        float4 st;
        st.x = acc[i4 * 4 + 0] + bias; st.y = acc[i4 * 4 + 1] + bias;
        st.z = acc[i4 * 4 + 2] + bias; st.w = acc[i4 * 4 + 3] + bias;
        *(float4*)&giT[(size_t)tid * NT + t0 + i4 * 4] = st;
    }

    // W_hh A-operand fragments: lane l holds A[m=l&15][k=8*(l>>4)+jj], jj=0..7.
    // Tile mt covers rows [16mt,16mt+16); wave w of gru owns mt in {w,w+4,w+8}.
    if (blockIdx.x == 0 && tid < 64) {
        const int l = tid, li = l & 15, q = l >> 4;
        for (int w = 0; w < 4; ++w)
            for (int ms = 0; ms < 3; ++ms)
                for (int kt = 0; kt < 2; ++kt) {
                    const int mt = w + 4 * ms;
                    unsigned short hi8[8], lo8[8];
#pragma unroll
                    for (int jj = 0; jj < 8; ++jj) {
                        const int m = mt * 16 + li;
                        const int k = kt * 32 + q * 8 + jj;
                        const float v = W_hh[m * HH + k];
                        const unsigned short h16 = f2bf(v);
                        hi8[jj] = h16;
                        lo8[jj] = f2bf(v - bf2f(h16));
                    }
                    const int fb = ((w * 3 + ms) * 2 + kt) * 2;
                    int4v a, b;
                    a.x = hi8[0] | (hi8[1] << 16); a.y = hi8[2] | (hi8[3] << 16);
                    a.z = hi8[4] | (hi8[5] << 16); a.w = hi8[6] | (hi8[7] << 16);
                    b.x = lo8[0] | (lo8[1] << 16); b.y = lo8[2] | (lo8[3] << 16);
                    b.z = lo8[4] | (lo8[5] << 16); b.w = lo8[6] | (lo8[7] << 16);
                    wfrag[(fb + 0) * 64 + l] = a;
                    wfrag[(fb + 1) * 64 + l] = b;
                }
    }
}

// Main kernel: block = 256 thr (4 waves) = 16 timesteps; grid = 2048.
// Per step: D'^T = W_hh.h^T via 18 mfma_f32_16x16x32_bf16 (split hi/lo, 3 products),
// D' C-layout: row=j-sub=4q+reg, col=t=lane&15. Wave w owns gate tiles {w,w+4,w+8}
// -> j' slice [16w,16w+16). h exchanged through double-buffered bf16 LDS, 1 barrier/step.
__global__ __launch_bounds__(256, 3) void gru_kernel(
    const float* __restrict__ giT, const int4v* __restrict__ wfrag,
    const float* __restrict__ b_hh, const float* __restrict__ W1,
    const float* __restrict__ b1, const float* __restrict__ W2,
    const float* __restrict__ b2, const int* __restrict__ dones,
    float* __restrict__ out)
{
    __shared__ unsigned short Hb[2][2][16 * 72];  // [buf][hi/lo][t*72 + k]
    __shared__ float Hfin[16 * 68];
    __shared__ float Hid[16 * 68];
    __shared__ int sfirst[16];

    const int tid = threadIdx.x;
    const int lane = tid & 63;
    const int w = tid >> 6;          // wave id = j-slice owner
    const int li = lane & 15;        // t within block (D' col)
    const int q = lane >> 4;         // quad
    const int T0 = blockIdx.x * 16;

    // W fragments -> registers (48 VGPRs bf16-packed per wave)
    bf16x8 whi[3][2], wlo[3][2];
#pragma unroll
    for (int ms = 0; ms < 3; ++ms)
#pragma unroll
        for (int kt = 0; kt < 2; ++kt) {
            const int fb = ((w * 3 + ms) * 2 + kt) * 2;
            frag_cast a, b;
            a.i4 = wfrag[(fb + 0) * 64 + lane];
            b.i4 = wfrag[(fb + 1) * 64 + lane];
            whi[ms][kt] = a.h8; wlo[ms][kt] = b.h8;
        }

    for (int x = tid; x < 2 * 16 * 72; x += 256) Hb[0][0][x] = 0;  // h0 = 0
    if (tid < 16) {
        const int t = T0 + tid;
        int lo = t - (LH - 1); if (lo < 0) lo = 0;
        int ws = lo;
        for (int j = t - 1; j >= lo; --j)
            if (dones[j] != 0) { ws = j + 1; break; }
        sfirst[tid] = ws - (t - (LH - 1));
    }
    __syncthreads();

    const int sfr = sfirst[li];
    float bnv[4];
    int rowoff[12];
#pragma unroll
    for (int rr = 0; rr < 4; ++rr) {
        const int jp = 16 * w + 4 * q + rr;        // this thread's j' for reg rr
        bnv[rr] = b_hh[128 + jp];
#pragma unroll
        for (int g = 0; g < 3; ++g)
            rowoff[g * 4 + rr] = (64 * g + jp) * NT;
    }
    const int gsbase = T0 + li - (LH - 1);

    float h[4] = {0.f, 0.f, 0.f, 0.f};

    for (int s = 0; s < LH; ++s) {
        const int buf = s & 1;
        // gi for this step (12 coalesced b32, L2-resident)
        int gidx = gsbase + s; if (gidx < 0) gidx = 0;   // masked when invalid
        float gv[12];
#pragma unroll
        for (int x = 0; x < 12; ++x) gv[x] = giT[rowoff[x] + gidx];

        // B-operand fragments: lane l holds h[t=l&15][k=8q+jj] (+32 for kt=1)
        bf16x8 bh[2], bl[2];
#pragma unroll
        for (int kt = 0; kt < 2; ++kt) {
            const int idx = 72 * li + kt * 32 + 8 * q;   // 16B-aligned
            bh[kt] = *(const bf16x8*)&Hb[buf][0][idx];
            bl[kt] = *(const bf16x8*)&Hb[buf][1][idx];
        }

        f32x4 acc[3];
#pragma unroll
        for (int ms = 0; ms < 3; ++ms) {
            f32x4 a = {0.f, 0.f, 0.f, 0.f};
            a = __builtin_amdgcn_mfma_f32_16x16x32_bf16(whi[ms][0], bh[0], a, 0, 0, 0);
            a = __builtin_amdgcn_mfma_f32_16x16x32_bf16(whi[ms][1], bh[1], a, 0, 0, 0);
            a = __builtin_amdgcn_mfma_f32_16x16x32_bf16(whi[ms][0], bl[0], a, 0, 0, 0);
            a = __builtin_amdgcn_mfma_f32_16x16x32_bf16(whi[ms][1], bl[1], a, 0, 0, 0);
            a = __builtin_amdgcn_mfma_f32_16x16x32_bf16(wlo[ms][0], bh[0], a, 0, 0, 0);
            a = __builtin_amdgcn_mfma_f32_16x16x32_bf16(wlo[ms][1], bh[1], a, 0, 0, 0);
            acc[ms] = a;
        }

        const bool valid = (s >= sfr);
        unsigned short nhi[4], nlo[4];
#pragma unroll
        for (int rr = 0; rr < 4; ++rr) {
            const float r  = fast_sigmoid(acc[0][rr] + gv[rr]);
            const float z  = fast_sigmoid(acc[1][rr] + gv[4 + rr]);
            const float nc = fast_tanh(gv[8 + rr] + r * (acc[2][rr] + bnv[rr]));
            const float hn = fmaf(z, h[rr] - nc, nc);
            h[rr] = valid ? hn : h[rr];
            nhi[rr] = f2bf(h[rr]);
            nlo[rr] = f2bf(h[rr] - bf2f(nhi[rr]));
        }
        {
            const int idx = 72 * li + 16 * w + 4 * q;     // 8B-aligned
            uint2 ph, pl;
            ph.x = nhi[0] | ((unsigned)nhi[1] << 16); ph.y = nhi[2] | ((unsigned)nhi[3] << 16);
            pl.x = nlo[0] | ((unsigned)nlo[1] << 16); pl.y = nlo[2] | ((unsigned)nlo[3] << 16);
            *(uint2*)&Hb[1 - buf][0][idx] = ph;
            *(uint2*)&Hb[1 - buf][1][idx] = pl;
        }
        __syncthreads();
    }

    // final h (fp32) -> LDS for the MLP
    {
        const int idx = 68 * li + 16 * w + 4 * q;         // 16B-aligned
        float4 st; st.x = h[0]; st.y = h[1]; st.z = h[2]; st.w = h[3];
        *(float4*)&Hfin[idx] = st;
    }
    __syncthreads();

    // MLP layer 1: thread (tt = tid&15, m0 = tid>>4) does m in {m0,+16,+32,+48}
    {
        const int tt = tid & 15, m0 = tid >> 4;
        float a0 = 0.f, a1 = 0.f, a2 = 0.f, a3 = 0.f;
        for (int k4 = 0; k4 < 16; ++k4) {
            const float4 hv = *(const float4*)&Hfin[68 * tt + k4 * 4];
            const float4 w0 = *(const float4*)&W1[(m0 +  0) * HH + k4 * 4];
            const float4 w1 = *(const float4*)&W1[(m0 + 16) * HH + k4 * 4];
            const float4 w2v = *(const float4*)&W1[(m0 + 32) * HH + k4 * 4];
            const float4 w3 = *(const float4*)&W1[(m0 + 48) * HH + k4 * 4];
            a0 += hv.x * w0.x + hv.y * w0.y + hv.z * w0.z + hv.w * w0.w;
            a1 += hv.x * w1.x + hv.y * w1.y + hv.z * w1.z + hv.w * w1.w;
            a2 += hv.x * w2v.x + hv.y * w2v.y + hv.z * w2v.z + hv.w * w2v.w;
            a3 += hv.x * w3.x + hv.y * w3.y + hv.z * w3.z + hv.w * w3.w;
        }
        Hid[68 * tt + m0 +  0] = fmaxf(a0 + b1[m0 +  0], 0.f);
        Hid[68 * tt + m0 + 16] = fmaxf(a1 + b1[m0 + 16], 0.f);
        Hid[68 * tt + m0 + 32] = fmaxf(a2 + b1[m0 + 32], 0.f);
        Hid[68 * tt + m0 + 48] = fmaxf(a3 + b1[m0 + 48], 0.f);
    }
    __syncthreads();

    // MLP layer 2: 64 outputs (16 t x 4 c) on wave 0
    if (tid < 64) {
        const int tt = tid >> 2, c = tid & 3;
        float a = b2[c];
        for (int m = 0; m < HH; ++m)
            a = fmaf(Hid[68 * tt + m], W2[c * HH + m], a);
        out[(size_t)(T0 + tt) * 4 + c] = a;
    }
}

extern "C" void kernel_launch(void* const* d_in, const int* in_sizes, int n_in,
                              void* d_out, int out_size, void* d_ws, size_t ws_size,
                              hipStream_t stream) {
    const float* emb  = (const float*)d_in[0];
    const float* W_ih = (const float*)d_in[1];
    const float* W_hh = (const float*)d_in[2];
    const float* b_ih = (const float*)d_in[3];
    const float* b_hh = (const float*)d_in[4];
    const float* W1   = (const float*)d_in[5];
    const float* b1   = (const float*)d_in[6];
    const float* W2   = (const float*)d_in[7];
    const float* b2   = (const float*)d_in[8];
    const int*   dn   = (const int*)d_in[9];

    float* giT   = (float*)d_ws;                                   // 25.2 MB
    int4v* wfrag = (int4v*)((char*)d_ws + (size_t)NT * G3 * 4);    // +48 KB
    float* o     = (float*)d_out;

    prep_kernel<<<NT / 32, 192, 0, stream>>>(emb, W_ih, b_ih, b_hh, W_hh, giT, wfrag);
    gru_kernel<<<NT / 16, 256, 0, stream>>>(giT, wfrag, b_hh, W1, b1, W2, b2, dn, o);
}

// Round 4
// 186.782 us; speedup vs baseline: 2.4935x; 1.0099x over previous
//
#include <hip/hip_runtime.h>

#define NT 32768
#define GST (NT + 16)   // padded giT row stride: kills 128KB channel aliasing
#define DI 36
#define HH 64
#define G3 192
#define LH 20
#define TPB 32          // timesteps per gru block

typedef __attribute__((ext_vector_type(8))) short bf16x8;
typedef __attribute__((ext_vector_type(4))) float f32x4;
typedef __attribute__((ext_vector_type(4))) int int4v;

union frag_cast { int4v i4; bf16x8 h8; };

__device__ __forceinline__ unsigned short f2bf(float f) {  // RNE fp32->bf16
    union { float f; unsigned u; } x; x.f = f;
    unsigned r = x.u + 0x7FFFu + ((x.u >> 16) & 1u);
    return (unsigned short)(r >> 16);
}
__device__ __forceinline__ float bf2f(unsigned short h) {
    union { float f; unsigned u; } x; x.u = ((unsigned)h) << 16;
    return x.f;
}
__device__ __forceinline__ float fast_sigmoid(float x) {
    return __builtin_amdgcn_rcpf(1.f + __builtin_amdgcn_exp2f(-1.44269504089f * x));
}
__device__ __forceinline__ float fast_tanh(float x) {
    return 1.f - 2.f * __builtin_amdgcn_rcpf(1.f + __builtin_amdgcn_exp2f(2.88539008178f * x));
}

// Kernel 1: gi[j][t] = emb[t,:].W_ih[j,:] + b_ih[j] + (j<128 ? b_hh[j] : 0),
// row-padded to GST. Stores go through an LDS transpose so each global store
// covers contiguous 128B t-segments (the R3 version's 128KB-stride scatter
// was ~75us of the runtime). Block 0 also emits W_hh MFMA A-fragments.
__global__ __launch_bounds__(192, 2) void prep_kernel(
    const float* __restrict__ emb, const float* __restrict__ W_ih,
    const float* __restrict__ b_ih, const float* __restrict__ b_hh,
    const float* __restrict__ W_hh,
    float* __restrict__ giT, int4v* __restrict__ wfrag)
{
    __shared__ float L[DI * 193 + DI * 36];
    float* const Wt = L;              // [k][j]  stride 193
    float* const Et = L + DI * 193;   // [k][ti] stride 36
    float* const Sg = L;              // reused after barrier: [j][t] stride 36
    const int tid = threadIdx.x;
    const int t0 = blockIdx.x * 32;

    for (int i = tid; i < G3 * DI; i += 192)
        Wt[(i % DI) * 193 + i / DI] = W_ih[i];
    for (int i = tid; i < 32 * DI; i += 192)
        Et[(i % DI) * 36 + i / DI] = emb[(size_t)t0 * DI + i];
    __syncthreads();

    float acc[32];
#pragma unroll
    for (int i = 0; i < 32; ++i) acc[i] = 0.f;
    for (int k = 0; k < DI; ++k) {
        const float w = Wt[k * 193 + tid];
#pragma unroll
        for (int i4 = 0; i4 < 8; ++i4) {
            const float4 e = *(const float4*)&Et[k * 36 + i4 * 4];  // broadcast
            acc[i4 * 4 + 0] = fmaf(e.x, w, acc[i4 * 4 + 0]);
            acc[i4 * 4 + 1] = fmaf(e.y, w, acc[i4 * 4 + 1]);
            acc[i4 * 4 + 2] = fmaf(e.z, w, acc[i4 * 4 + 2]);
            acc[i4 * 4 + 3] = fmaf(e.w, w, acc[i4 * 4 + 3]);
        }
    }
    const float bias = b_ih[tid] + (tid < 128 ? b_hh[tid] : 0.f);
    __syncthreads();                              // done reading Wt
#pragma unroll
    for (int i4 = 0; i4 < 8; ++i4) {
        float4 st;
        st.x = acc[i4 * 4 + 0] + bias; st.y = acc[i4 * 4 + 1] + bias;
        st.z = acc[i4 * 4 + 2] + bias; st.w = acc[i4 * 4 + 3] + bias;
        *(float4*)&Sg[tid * 36 + i4 * 4] = st;    // [j][t] local
    }
    __syncthreads();
    // store out: thread -> float4 #(it*192+tid); 8 lanes = one 128B t-chunk
#pragma unroll
    for (int it = 0; it < 8; ++it) {
        const int idx = it * 192 + tid;
        const int j = idx >> 3, tq = idx & 7;
        *(float4*)&giT[(size_t)j * GST + t0 + 4 * tq] =
            *(const float4*)&Sg[j * 36 + 4 * tq];
    }

    // W_hh A-fragments: lane l holds A[m=l&15][k=8*(l>>4)+jj] (verified R3)
    if (blockIdx.x == 0 && tid < 64) {
        const int l = tid, li = l & 15, q = l >> 4;
        for (int w = 0; w < 4; ++w)
            for (int ms = 0; ms < 3; ++ms)
                for (int kt = 0; kt < 2; ++kt) {
                    const int mt = w + 4 * ms;
                    unsigned short hi8[8], lo8[8];
#pragma unroll
                    for (int jj = 0; jj < 8; ++jj) {
                        const int m = mt * 16 + li;
                        const int k = kt * 32 + q * 8 + jj;
                        const float v = W_hh[m * HH + k];
                        const unsigned short h16 = f2bf(v);
                        hi8[jj] = h16;
                        lo8[jj] = f2bf(v - bf2f(h16));
                    }
                    const int fb = ((w * 3 + ms) * 2 + kt) * 2;
                    int4v a, b;
                    a.x = hi8[0] | (hi8[1] << 16); a.y = hi8[2] | (hi8[3] << 16);
                    a.z = hi8[4] | (hi8[5] << 16); a.w = hi8[6] | (hi8[7] << 16);
                    b.x = lo8[0] | (lo8[1] << 16); b.y = lo8[2] | (lo8[3] << 16);
                    b.z = lo8[4] | (lo8[5] << 16); b.w = lo8[6] | (lo8[7] << 16);
                    wfrag[(fb + 0) * 64 + l] = a;
                    wfrag[(fb + 1) * 64 + l] = b;
                }
    }
}

// Main kernel: block = 4 waves = 32 timesteps (2 t-tiles), grid 1024.
// Wave w owns j' slice [16w,16w+16) of all 3 gates; per step per tile:
// 18 mfma (3 chains of 6, split bf16 hi/lo); 6 independent chains per step.
// gv (precomputed input gates) prefetched one step ahead (registers).
__global__ __launch_bounds__(256, 2) void gru_kernel(
    const float* __restrict__ giT, const int4v* __restrict__ wfrag,
    const float* __restrict__ b_hh, const float* __restrict__ W1,
    const float* __restrict__ b1, const float* __restrict__ W2,
    const float* __restrict__ b2, const int* __restrict__ dones,
    float* __restrict__ out)
{
    __shared__ __align__(16) char Sraw[4 * 2304 * 2];   // 18.4 KB
    unsigned short* const Hb = (unsigned short*)Sraw;   // [buf][hl][t*72+k]
    float* const Hfin = (float*)Sraw;                   // after loop: [t][k] s68
    float* const Hid  = (float*)(Sraw + 8704);          // [t][m] s68
    __shared__ int sfirst[TPB];

    const int tid = threadIdx.x;
    const int lane = tid & 63;
    const int w = tid >> 6;
    const int li = lane & 15;
    const int q = lane >> 4;
    const int T0 = blockIdx.x * TPB;

    bf16x8 whi[3][2], wlo[3][2];
#pragma unroll
    for (int ms = 0; ms < 3; ++ms)
#pragma unroll
        for (int kt = 0; kt < 2; ++kt) {
            const int fb = ((w * 3 + ms) * 2 + kt) * 2;
            frag_cast a, b;
            a.i4 = wfrag[(fb + 0) * 64 + lane];
            b.i4 = wfrag[(fb + 1) * 64 + lane];
            whi[ms][kt] = a.h8; wlo[ms][kt] = b.h8;
        }

    for (int x = tid; x < 4608; x += 256) Hb[x] = 0;    // buf0 hi+lo = h0
    if (tid < TPB) {
        const int t = T0 + tid;
        int lo = t - (LH - 1); if (lo < 0) lo = 0;
        int ws = lo;
        for (int j = t - 1; j >= lo; --j)
            if (dones[j] != 0) { ws = j + 1; break; }
        sfirst[tid] = ws - (t - (LH - 1));
    }
    __syncthreads();

    const int sfr0 = sfirst[li];
    const int sfr1 = sfirst[16 + li];
    float bnv[4];
    int rowoff[12];
#pragma unroll
    for (int rr = 0; rr < 4; ++rr) {
        const int jp = 16 * w + 4 * q + rr;
        bnv[rr] = b_hh[128 + jp];
#pragma unroll
        for (int g = 0; g < 3; ++g)
            rowoff[g * 4 + rr] = (64 * g + jp) * GST;
    }
    const int gb0 = T0 + li - (LH - 1);
    const int gb1 = gb0 + 16;

    float gv[2][24];   // [parity][tile*12 + x]
    {
        const int g0 = gb0 < 0 ? 0 : gb0;
        const int g1 = gb1 < 0 ? 0 : gb1;
#pragma unroll
        for (int x = 0; x < 12; ++x) {
            gv[0][x]      = giT[rowoff[x] + g0];
            gv[0][12 + x] = giT[rowoff[x] + g1];
        }
    }

    float h[8] = {0.f, 0.f, 0.f, 0.f, 0.f, 0.f, 0.f, 0.f};

#pragma unroll 2
    for (int s = 0; s < LH; ++s) {
        const int p = s & 1;
        // prefetch gv for step s+1 (s=19's prefetch lands in row pad: unused)
        {
            int g0 = gb0 + s + 1; g0 = g0 < 0 ? 0 : g0;
            int g1 = gb1 + s + 1; g1 = g1 < 0 ? 0 : g1;
#pragma unroll
            for (int x = 0; x < 12; ++x) {
                gv[1 - p][x]      = giT[rowoff[x] + g0];
                gv[1 - p][12 + x] = giT[rowoff[x] + g1];
            }
        }
#pragma unroll
        for (int tile = 0; tile < 2; ++tile) {
            const int tb = (16 * tile + li) * 72;
            const int rb = p * 4608;
            const bf16x8 bh0 = *(const bf16x8*)&Hb[rb + tb + 8 * q];
            const bf16x8 bh1 = *(const bf16x8*)&Hb[rb + tb + 32 + 8 * q];
            const bf16x8 bl0 = *(const bf16x8*)&Hb[rb + 2304 + tb + 8 * q];
            const bf16x8 bl1 = *(const bf16x8*)&Hb[rb + 2304 + tb + 32 + 8 * q];

            f32x4 acc[3];
#pragma unroll
            for (int ms = 0; ms < 3; ++ms) {
                f32x4 a = {0.f, 0.f, 0.f, 0.f};
                a = __builtin_amdgcn_mfma_f32_16x16x32_bf16(whi[ms][0], bh0, a, 0, 0, 0);
                a = __builtin_amdgcn_mfma_f32_16x16x32_bf16(whi[ms][1], bh1, a, 0, 0, 0);
                a = __builtin_amdgcn_mfma_f32_16x16x32_bf16(whi[ms][0], bl0, a, 0, 0, 0);
                a = __builtin_amdgcn_mfma_f32_16x16x32_bf16(whi[ms][1], bl1, a, 0, 0, 0);
                a = __builtin_amdgcn_mfma_f32_16x16x32_bf16(wlo[ms][0], bh0, a, 0, 0, 0);
                a = __builtin_amdgcn_mfma_f32_16x16x32_bf16(wlo[ms][1], bh1, a, 0, 0, 0);
                acc[ms] = a;
            }

            const bool valid = (s >= (tile == 0 ? sfr0 : sfr1));
            unsigned short nhi[4], nlo[4];
#pragma unroll
            for (int rr = 0; rr < 4; ++rr) {
                const float r  = fast_sigmoid(acc[0][rr] + gv[p][tile * 12 + rr]);
                const float z  = fast_sigmoid(acc[1][rr] + gv[p][tile * 12 + 4 + rr]);
                const float nc = fast_tanh(gv[p][tile * 12 + 8 + rr] + r * (acc[2][rr] + bnv[rr]));
                const float hn = fmaf(z, h[tile * 4 + rr] - nc, nc);
                h[tile * 4 + rr] = valid ? hn : h[tile * 4 + rr];
                nhi[rr] = f2bf(h[tile * 4 + rr]);
                nlo[rr] = f2bf(h[tile * 4 + rr] - bf2f(nhi[rr]));
            }
            {
                const int wb = (1 - p) * 4608;
                const int idx = tb + 16 * w + 4 * q;
                uint2 ph, pl;
                ph.x = nhi[0] | ((unsigned)nhi[1] << 16); ph.y = nhi[2] | ((unsigned)nhi[3] << 16);
                pl.x = nlo[0] | ((unsigned)nlo[1] << 16); pl.y = nlo[2] | ((unsigned)nlo[3] << 16);
                *(uint2*)&Hb[wb + idx] = ph;
                *(uint2*)&Hb[wb + 2304 + idx] = pl;
            }
        }
        __syncthreads();
    }

    // final h -> LDS (fp32) for MLP
#pragma unroll
    for (int tile = 0; tile < 2; ++tile) {
        float4 st;
        st.x = h[tile * 4 + 0]; st.y = h[tile * 4 + 1];
        st.z = h[tile * 4 + 2]; st.w = h[tile * 4 + 3];
        *(float4*)&Hfin[68 * (16 * tile + li) + 16 * w + 4 * q] = st;
    }
    __syncthreads();

    // MLP layer 1: thread (tt=tid&31, m-block=tid>>5) does 8 consecutive m
    {
        const int tt = tid & 31, m0 = (tid >> 5) * 8;
        float a[8];
#pragma unroll
        for (int mm = 0; mm < 8; ++mm) a[mm] = 0.f;
        for (int k4 = 0; k4 < 16; ++k4) {
            const float4 hv = *(const float4*)&Hfin[68 * tt + 4 * k4];
#pragma unroll
            for (int mm = 0; mm < 8; ++mm) {
                const float4 wv = *(const float4*)&W1[(m0 + mm) * HH + 4 * k4];
                a[mm] += hv.x * wv.x + hv.y * wv.y + hv.z * wv.z + hv.w * wv.w;
            }
        }
        __syncthreads();
#pragma unroll
        for (int mm = 0; mm < 8; ++mm)
            Hid[68 * tt + m0 + mm] = fmaxf(a[mm] + b1[m0 + mm], 0.f);
    }
    __syncthreads();

    // MLP layer 2: 128 outputs (32 t x 4 c)
    if (tid < 128) {
        const int tt = tid >> 2, c = tid & 3;
        float acc2 = b2[c];
        for (int m4 = 0; m4 < 16; ++m4) {
            const float4 hv = *(const float4*)&Hid[68 * tt + 4 * m4];
            const float4 wv = *(const float4*)&W2[c * HH + 4 * m4];
            acc2 += hv.x * wv.x + hv.y * wv.y + hv.z * wv.z + hv.w * wv.w;
        }
        out[(size_t)(T0 + tt) * 4 + c] = acc2;
    }
}

extern "C" void kernel_launch(void* const* d_in, const int* in_sizes, int n_in,
                              void* d_out, int out_size, void* d_ws, size_t ws_size,
                              hipStream_t stream) {
    const float* emb  = (const float*)d_in[0];
    const float* W_ih = (const float*)d_in[1];
    const float* W_hh = (const float*)d_in[2];
    const float* b_ih = (const float*)d_in[3];
    const float* b_hh = (const float*)d_in[4];
    const float* W1   = (const float*)d_in[5];
    const float* b1   = (const float*)d_in[6];
    const float* W2   = (const float*)d_in[7];
    const float* b2   = (const float*)d_in[8];
    const int*   dn   = (const int*)d_in[9];

    float* giT   = (float*)d_ws;                                    // 25.2 MB
    int4v* wfrag = (int4v*)((char*)d_ws + (size_t)G3 * GST * 4);    // +48 KB
    float* o     = (float*)d_out;

    prep_kernel<<<NT / 32, 192, 0, stream>>>(emb, W_ih, b_ih, b_hh, W_hh, giT, wfrag);
    gru_kernel<<<NT / TPB, 256, 0, stream>>>(giT, wfrag, b_hh, W1, b1, W2, b2, dn, o);
}